// Round 7
// baseline (367.382 us; speedup 1.0000x reference)
//
#include <hip/hip_runtime.h>
#include <cstdint>
#include <type_traits>

typedef unsigned short u16;
typedef __attribute__((ext_vector_type(8))) short short8;    // 8 bf16 (4 VGPRs)
typedef __attribute__((ext_vector_type(8))) __fp16 half8;    // 8 fp16 (4 VGPRs)
typedef __attribute__((ext_vector_type(2))) __fp16 half2v;
typedef __attribute__((ext_vector_type(4))) float f32x4;

#define DMODEL 1024
#define TSEQ   2048
#define NHEADS 16
#define DKH    64
#define NBATCH 4
#define MROWS  (NBATCH * TSEQ)   // 8192
#define QSCALE 0.18033688011f    // 0.125 * log2(e), folded into Q projection

// ---------- conversions ----------
__device__ __forceinline__ float b2f(u16 u) {
  union { unsigned int u; float f; } c; c.u = ((unsigned int)u) << 16; return c.f;
}
__device__ __forceinline__ u16 f2b(float f) {   // f32->bf16 RNE
  union { float f; unsigned int u; } c; c.f = f;
  unsigned int u = c.u;
  return (u16)((u + 0x7fffu + ((u >> 16) & 1u)) >> 16);
}
__device__ __forceinline__ half2v pkrtz(float a, float b) {
  return __builtin_amdgcn_cvt_pkrtz(a, b);      // v_cvt_pkrtz_f16_f32
}
__device__ __forceinline__ unsigned h2u(half2v h) {
  unsigned u; __builtin_memcpy(&u, &h, 4); return u;
}
__device__ __forceinline__ u16 f2h(float f) {   // f32->fp16 RTZ
  half2v h = pkrtz(f, 0.f);
  u16 u; __builtin_memcpy(&u, &h, 2); return u;
}

// ---------- async global->LDS, 16B/lane ----------
__device__ __forceinline__ void gl_lds16(const u16* g, u16* l) {
  __builtin_amdgcn_global_load_lds((const __attribute__((address_space(1))) void*)g,
                                   (__attribute__((address_space(3))) void*)l, 16, 0, 0);
}

// ---------- bulk f32 -> bf16, z picks tensor (x_q / x_v) ----------
__global__ void cvt_bf16(const float* __restrict__ in0, u16* __restrict__ out0,
                         const float* __restrict__ in1, u16* __restrict__ out1) {
  const float* in = blockIdx.z ? in1 : in0;
  u16* out = blockIdx.z ? out1 : out0;
  int i = blockIdx.x * 256 + threadIdx.x;
  const float4* p = (const float4*)in + (long long)i * 2;
  float4 a = p[0], b = p[1];
  union { u16 s[8]; uint4 v; } pk;
  pk.s[0] = f2b(a.x); pk.s[1] = f2b(a.y); pk.s[2] = f2b(a.z); pk.s[3] = f2b(a.w);
  pk.s[4] = f2b(b.x); pk.s[5] = f2b(b.y); pk.s[6] = f2b(b.z); pk.s[7] = f2b(b.w);
  ((uint4*)out)[i] = pk.v;
}

// ---------- 1024x1024 transpose + convert; z=0,1 -> bf16 (Wq,Wv), z=2 -> f16 (Wf) ----------
__global__ void transpose_cvt(const float* __restrict__ w0, u16* __restrict__ o0,
                              const float* __restrict__ w1, u16* __restrict__ o1,
                              const float* __restrict__ w2, u16* __restrict__ o2) {
  const int z = blockIdx.z;
  const float* in = (z == 0) ? w0 : (z == 1) ? w1 : w2;
  u16* out = (z == 0) ? o0 : (z == 1) ? o1 : o2;
  __shared__ float t[32][33];
  int bx = blockIdx.x * 32, by = blockIdx.y * 32;
  int tx = threadIdx.x, ty = threadIdx.y;   // (32,8)
  #pragma unroll
  for (int i = ty; i < 32; i += 8)
    t[i][tx] = in[(by + i) * DMODEL + bx + tx];
  __syncthreads();
  #pragma unroll
  for (int i = ty; i < 32; i += 8)
    out[(bx + i) * DMODEL + by + tx] = (z == 2) ? f2h(t[tx][i]) : f2b(t[tx][i]);
}

// ---------- per-head V transpose, bf16 -> f16: VbT[((nb*16+h)*64+d)*T + t] ----------
__global__ void transpose_v(const u16* __restrict__ Vb, u16* __restrict__ VbT) {
  __shared__ u16 tl[64 * 66];
  int tb = blockIdx.x, h = blockIdx.y, nb = blockIdx.z;
  int tx = threadIdx.x, ty = threadIdx.y;   // (64,4)
  long long src = (long long)(nb * TSEQ + tb * 64) * DMODEL + h * DKH;
  #pragma unroll
  for (int r = ty; r < 64; r += 4)
    tl[r * 66 + tx] = Vb[src + (long long)r * DMODEL + tx];
  __syncthreads();
  long long dst = (long long)((nb * NHEADS + h) * DKH) * TSEQ + tb * 64;
  #pragma unroll
  for (int r = ty; r < 64; r += 4)
    VbT[dst + (long long)r * TSEQ + tx] = f2h(b2f(tl[tx * 66 + r]));
}

// ---------- GEMM core: C[M,N] = A[M,K] @ Bt[N,K]^T + bias, 128x64 tile, BK=64 ----------
// 4 waves (2x2), wave tile 64x32. Small tile -> 4-8 blocks/CU for latency hiding.
template <bool F16, typename CT>
__device__ __forceinline__ void gemm_core(
    u16* As, u16* Bs,   // As[128*64], Bs[64*64]
    const u16* __restrict__ A, const u16* __restrict__ Bt,
    const float* __restrict__ bias, CT* __restrict__ C,
    const int bm, const int bn, const float osc) {
  const int tid  = threadIdx.x;
  const int wv   = tid >> 6, lane = tid & 63;
  const int wm   = wv >> 1, wn = wv & 1;
  const int l15  = lane & 15, quad = lane >> 4;
  const int srow = lane >> 3, gch = (lane & 7) ^ srow;

  f32x4 acc[4][2];
  #pragma unroll
  for (int i = 0; i < 4; ++i)
    #pragma unroll
    for (int j = 0; j < 2; ++j)
      acc[i][j] = (f32x4){0.f, 0.f, 0.f, 0.f};

  const u16* Ag = A  + (long long)(bm * 128) * DMODEL;
  const u16* Bg = Bt + (long long)(bn * 64) * DMODEL;

  for (int k0 = 0; k0 < DMODEL; k0 += 64) {
    __syncthreads();
    #pragma unroll
    for (int j = 0; j < 4; ++j) {            // A: 128 rows
      int rb = wv * 32 + j * 8;
      gl_lds16(Ag + (long long)(rb + srow) * DMODEL + k0 + gch * 8, As + rb * 64);
    }
    #pragma unroll
    for (int j = 0; j < 2; ++j) {            // B: 64 rows
      int rb = wv * 16 + j * 8;
      gl_lds16(Bg + (long long)(rb + srow) * DMODEL + k0 + gch * 8, Bs + rb * 64);
    }
    __syncthreads();
    #pragma unroll
    for (int ks = 0; ks < 2; ++ks) {
      short8 af[4], bf_[2];
      #pragma unroll
      for (int mi = 0; mi < 4; ++mi) {
        int ra = wm * 64 + mi * 16 + l15;
        af[mi] = *(const short8*)(As + ra * 64 + (((ks * 4 + quad) ^ (ra & 7)) * 8));
      }
      #pragma unroll
      for (int ni = 0; ni < 2; ++ni) {
        int rb = wn * 32 + ni * 16 + l15;
        bf_[ni] = *(const short8*)(Bs + rb * 64 + (((ks * 4 + quad) ^ (rb & 7)) * 8));
      }
      #pragma unroll
      for (int mi = 0; mi < 4; ++mi)
        #pragma unroll
        for (int ni = 0; ni < 2; ++ni) {
          if constexpr (F16)
            acc[mi][ni] = __builtin_amdgcn_mfma_f32_16x16x32_f16(
                *(const half8*)&af[mi], *(const half8*)&bf_[ni], acc[mi][ni], 0, 0, 0);
          else
            acc[mi][ni] = __builtin_amdgcn_mfma_f32_16x16x32_bf16(
                af[mi], bf_[ni], acc[mi][ni], 0, 0, 0);
        }
    }
  }

  #pragma unroll
  for (int ni = 0; ni < 2; ++ni) {
    int col = bn * 64 + wn * 32 + ni * 16 + l15;
    float bvf = bias[col];
    #pragma unroll
    for (int mi = 0; mi < 4; ++mi) {
      int row0 = bm * 128 + wm * 64 + mi * 16 + quad * 4;
      #pragma unroll
      for (int r = 0; r < 4; ++r) {
        float val = (acc[mi][ni][r] + bvf) * osc;
        long long idx = (long long)(row0 + r) * DMODEL + col;
        if constexpr (std::is_same_v<CT, float>) C[idx] = val;
        else                                     C[idx] = f2b(val);
      }
    }
  }
}

// Q and V projections fused on grid z (grid 64x16x2 = 2048 blocks)
__global__ __launch_bounds__(256, 6)
void gemm_qv(const u16* __restrict__ Xq, const u16* __restrict__ Xv,
             const u16* __restrict__ WqT, const u16* __restrict__ WvT,
             const float* __restrict__ bq, const float* __restrict__ bv,
             u16* __restrict__ Qb, u16* __restrict__ Vb) {
  __shared__ u16 As[128 * 64];
  __shared__ u16 Bs[64 * 64];
  const bool isq = (blockIdx.z == 0);
  gemm_core<false, u16>(As, Bs, isq ? Xq : Xv, isq ? WqT : WvT,
                        isq ? bq : bv, isq ? Qb : Vb,
                        blockIdx.x, blockIdx.y, isq ? QSCALE : 1.0f);
}

// out projection: f16 x f16 -> f32 (grid 64x16 = 1024 blocks)
__global__ __launch_bounds__(256, 6)
void gemm_out(const u16* __restrict__ A, const u16* __restrict__ Bt,
              const float* __restrict__ bias, float* __restrict__ C) {
  __shared__ u16 As[128 * 64];
  __shared__ u16 Bs[64 * 64];
  gemm_core<true, float>(As, Bs, A, Bt, bias, C, blockIdx.x, blockIdx.y, 1.0f);
}

// ---------- Flash attention, S^T form, scale pre-folded into Q ----------
// S^T = V Q'^T (exp2 domain); P = exp2(S^T [+mask]); O^T = V^T P^T; l via ones-MFMA.
__global__ __launch_bounds__(256, 4)
void attn_kernel(const u16* __restrict__ Qb, const u16* __restrict__ Vb,
                 const u16* __restrict__ VbTh, const int* __restrict__ mask,
                 u16* __restrict__ Ab) {
  __shared__ u16 Vs[64 * 64];        // [t][d] bf16, swizzled
  __shared__ u16 Vts[64 * 64];       // [d][t] f16, swizzled
  __shared__ u16 Ps[4 * 32 * 72];    // per-wave P [q][t] f16, stride 72
  __shared__ float Msf[64];          // additive mask

  const int tid  = threadIdx.x;
  const int qblk = blockIdx.x, h = blockIdx.y, nb = blockIdx.z;
  const int wv   = tid >> 6, lane = tid & 63;
  const int l15  = lane & 15, quad = lane >> 4;
  const int srow = lane >> 3, gch = (lane & 7) ^ srow;

  const int q0 = qblk * 128 + wv * 32;
  const long long rowbase = (long long)nb * TSEQ;
  const long long hd = (long long)((nb * NHEADS + h) * DKH);
  u16* psb = Ps + wv * 32 * 72;

  short8 qf[2][2];   // Q' B-frags (pre-scaled), loaded once
  #pragma unroll
  for (int mi = 0; mi < 2; ++mi)
    #pragma unroll
    for (int ks = 0; ks < 2; ++ks)
      qf[mi][ks] = *(const short8*)(Qb + (rowbase + q0 + mi * 16 + l15) * DMODEL
                                    + h * DKH + ks * 32 + quad * 8);

  f32x4 of[2][4];
  f32x4 lacc[2];     // l per q (col l15), rows redundant
  #pragma unroll
  for (int mi = 0; mi < 2; ++mi) {
    lacc[mi] = (f32x4){0.f, 0.f, 0.f, 0.f};
    #pragma unroll
    for (int dt = 0; dt < 4; ++dt)
      of[mi][dt] = (f32x4){0.f, 0.f, 0.f, 0.f};
  }
  const half8 ones8 = {(__fp16)1.f, (__fp16)1.f, (__fp16)1.f, (__fp16)1.f,
                       (__fp16)1.f, (__fp16)1.f, (__fp16)1.f, (__fp16)1.f};

  for (int vb = 0; vb < TSEQ / 64; ++vb) {
    __syncthreads();
    #pragma unroll
    for (int j = 0; j < 2; ++j) {
      int rb = wv * 16 + j * 8;
      gl_lds16(Vb   + (rowbase + vb * 64 + rb + srow) * DMODEL + h * DKH + gch * 8, Vs  + rb * 64);
      gl_lds16(VbTh + (hd + rb + srow) * TSEQ + vb * 64 + gch * 8,                  Vts + rb * 64);
    }
    int mv = mask[nb * TSEQ + vb * 64 + lane];
    if (tid < 64) Msf[tid] = mv ? 0.f : -INFINITY;
    const bool slowm = __any(mv == 0);   // wave-uniform
    __syncthreads();

    // ---- S^T = V @ Q'^T ----
    f32x4 st[2][4];
    #pragma unroll
    for (int mi = 0; mi < 2; ++mi)
      #pragma unroll
      for (int tt = 0; tt < 4; ++tt)
        st[mi][tt] = (f32x4){0.f, 0.f, 0.f, 0.f};
    #pragma unroll
    for (int tt = 0; tt < 4; ++tt) {
      int r = tt * 16 + l15;
      #pragma unroll
      for (int ks = 0; ks < 2; ++ks) {
        short8 vf = *(const short8*)(Vs + r * 64 + (((ks * 4 + quad) ^ (l15 & 7)) * 8));
        #pragma unroll
        for (int mi = 0; mi < 2; ++mi)
          st[mi][tt] = __builtin_amdgcn_mfma_f32_16x16x32_bf16(vf, qf[mi][ks], st[mi][tt], 0, 0, 0);
      }
    }

    // ---- P = exp2(st [+mask]); fp16 pack; write Ps ----
    f32x4 msk[4];
    if (slowm) {
      #pragma unroll
      for (int tt = 0; tt < 4; ++tt)
        msk[tt] = *(const f32x4*)(Msf + tt * 16 + quad * 4);
    }
    #pragma unroll
    for (int mi = 0; mi < 2; ++mi) {
      #pragma unroll
      for (int tt = 0; tt < 4; ++tt) {
        float a0 = st[mi][tt][0], a1 = st[mi][tt][1];
        float a2 = st[mi][tt][2], a3 = st[mi][tt][3];
        if (slowm) { a0 += msk[tt][0]; a1 += msk[tt][1]; a2 += msk[tt][2]; a3 += msk[tt][3]; }
        float p0 = __builtin_amdgcn_exp2f(a0);
        float p1 = __builtin_amdgcn_exp2f(a1);
        float p2 = __builtin_amdgcn_exp2f(a2);
        float p3 = __builtin_amdgcn_exp2f(a3);
        uint2 pk; pk.x = h2u(pkrtz(p0, p1)); pk.y = h2u(pkrtz(p2, p3));
        *(uint2*)(psb + (mi * 16 + l15) * 72 + tt * 16 + quad * 4) = pk;
      }
    }

    // ---- O^T += V^T @ P^T; l += ones @ P^T (matrix-pipe row-sum) ----
    #pragma unroll
    for (int kc = 0; kc < 2; ++kc) {
      half8 pf[2];
      #pragma unroll
      for (int mi = 0; mi < 2; ++mi)
        pf[mi] = *(const half8*)(psb + (mi * 16 + l15) * 72 + kc * 32 + quad * 8);
      #pragma unroll
      for (int mi = 0; mi < 2; ++mi)
        lacc[mi] = __builtin_amdgcn_mfma_f32_16x16x32_f16(ones8, pf[mi], lacc[mi], 0, 0, 0);
      #pragma unroll
      for (int dt = 0; dt < 4; ++dt) {
        int r = dt * 16 + l15;
        half8 vtf = *(const half8*)(Vts + r * 64 + (((kc * 4 + quad) ^ (l15 & 7)) * 8));
        #pragma unroll
        for (int mi = 0; mi < 2; ++mi)
          of[mi][dt] = __builtin_amdgcn_mfma_f32_16x16x32_f16(vtf, pf[mi], of[mi][dt], 0, 0, 0);
      }
    }
  }

  // ---- epilogue: O^T/l -> Ab (f16), 8B packed stores; l already lane-local ----
  #pragma unroll
  for (int mi = 0; mi < 2; ++mi) {
    float inv = 1.0f / lacc[mi][0];
    long long row = rowbase + q0 + mi * 16 + l15;
    #pragma unroll
    for (int dt = 0; dt < 4; ++dt) {
      uint2 o;
      o.x = h2u(pkrtz(of[mi][dt][0] * inv, of[mi][dt][1] * inv));
      o.y = h2u(pkrtz(of[mi][dt][2] * inv, of[mi][dt][3] * inv));
      *(uint2*)(Ab + row * DMODEL + h * DKH + dt * 16 + quad * 4) = o;
    }
  }
}

// ---------- launch ----------
extern "C" void kernel_launch(void* const* d_in, const int* in_sizes, int n_in,
                              void* d_out, int out_size, void* d_ws, size_t ws_size,
                              hipStream_t stream) {
  // order: x_k(0) x_v(1) x_q(2) mask(3) Wk(4) bk(5) Wv(6) bv(7) Wq(8) bq(9) Wf(10) bf(11)
  const float* x_v  = (const float*)d_in[1];
  const float* x_q  = (const float*)d_in[2];
  const int*   mask = (const int*)d_in[3];
  const float* Wv   = (const float*)d_in[6];
  const float* bv   = (const float*)d_in[7];
  const float* Wq   = (const float*)d_in[8];
  const float* bq   = (const float*)d_in[9];
  const float* Wf   = (const float*)d_in[10];
  const float* bfp  = (const float*)d_in[11];

  char* w = (char*)d_ws;
  u16* WqT  = (u16*)(w + 0);            // bf16, 2 MB
  u16* WvT  = (u16*)(w + (2ll << 20));  // bf16
  u16* WfT  = (u16*)(w + (4ll << 20));  // f16
  u16* Xq   = (u16*)(w + (6ll << 20));  // bf16, 16 MB
  u16* Xv   = (u16*)(w + (22ll << 20)); // bf16
  u16* Qb   = (u16*)(w + (38ll << 20)); // bf16 (pre-scaled by QSCALE)
  u16* Vb   = (u16*)(w + (54ll << 20)); // bf16
  u16* VbTh = (u16*)(w + (70ll << 20)); // f16
  u16* Ab   = Xq;                       // f16; alias ok (Xq dead after QV GEMM)

  transpose_cvt<<<dim3(32, 32, 3), dim3(32, 8), 0, stream>>>(Wq, WqT, Wv, WvT, Wf, WfT);

  cvt_bf16<<<dim3(MROWS * DMODEL / 8 / 256, 1, 2), 256, 0, stream>>>(x_q, Xq, x_v, Xv);

  gemm_qv<<<dim3(MROWS / 128, DMODEL / 64, 2), 256, 0, stream>>>(
      Xq, Xv, WqT, WvT, bq, bv, Qb, Vb);

  transpose_v<<<dim3(TSEQ / 64, NHEADS, NBATCH), dim3(64, 4), 0, stream>>>(Vb, VbTh);

  attn_kernel<<<dim3(TSEQ / 128, NHEADS, NBATCH), 256, 0, stream>>>(Qb, Vb, VbTh, mask, Ab);

  gemm_out<<<dim3(MROWS / 128, DMODEL / 64), 256, 0, stream>>>(Ab, WfT, bfp, (float*)d_out);
}

// Round 8
// 340.257 us; speedup vs baseline: 1.0797x; 1.0797x over previous
//
#include <hip/hip_runtime.h>
#include <cstdint>
#include <type_traits>

typedef unsigned short u16;
typedef __attribute__((ext_vector_type(8))) short short8;    // 8 bf16 (4 VGPRs)
typedef __attribute__((ext_vector_type(8))) __fp16 half8;    // 8 fp16 (4 VGPRs)
typedef __attribute__((ext_vector_type(2))) __fp16 half2v;
typedef __attribute__((ext_vector_type(4))) float f32x4;

#define DMODEL 1024
#define TSEQ   2048
#define NHEADS 16
#define DKH    64
#define NBATCH 4
#define MROWS  (NBATCH * TSEQ)   // 8192
#define QSCALE 0.18033688011f    // 0.125 * log2(e), folded into Q projection

// ---------- conversions ----------
__device__ __forceinline__ float b2f(u16 u) {
  union { unsigned int u; float f; } c; c.u = ((unsigned int)u) << 16; return c.f;
}
__device__ __forceinline__ u16 f2b(float f) {   // f32->bf16 RNE
  union { float f; unsigned int u; } c; c.f = f;
  unsigned int u = c.u;
  return (u16)((u + 0x7fffu + ((u >> 16) & 1u)) >> 16);
}
__device__ __forceinline__ half2v pkrtz(float a, float b) {
  return __builtin_amdgcn_cvt_pkrtz(a, b);      // v_cvt_pkrtz_f16_f32
}
__device__ __forceinline__ unsigned h2u(half2v h) {
  unsigned u; __builtin_memcpy(&u, &h, 4); return u;
}
__device__ __forceinline__ u16 f2h(float f) {   // f32->fp16 RTZ
  half2v h = pkrtz(f, 0.f);
  u16 u; __builtin_memcpy(&u, &h, 2); return u;
}

// ---------- async global->LDS, 16B/lane ----------
__device__ __forceinline__ void gl_lds16(const u16* g, u16* l) {
  __builtin_amdgcn_global_load_lds((const __attribute__((address_space(1))) void*)g,
                                   (__attribute__((address_space(3))) void*)l, 16, 0, 0);
}

// ---------- bulk f32 -> bf16, z picks tensor (x_q / x_v) ----------
__global__ void cvt_bf16(const float* __restrict__ in0, u16* __restrict__ out0,
                         const float* __restrict__ in1, u16* __restrict__ out1) {
  const float* in = blockIdx.z ? in1 : in0;
  u16* out = blockIdx.z ? out1 : out0;
  int i = blockIdx.x * 256 + threadIdx.x;
  const float4* p = (const float4*)in + (long long)i * 2;
  float4 a = p[0], b = p[1];
  union { u16 s[8]; uint4 v; } pk;
  pk.s[0] = f2b(a.x); pk.s[1] = f2b(a.y); pk.s[2] = f2b(a.z); pk.s[3] = f2b(a.w);
  pk.s[4] = f2b(b.x); pk.s[5] = f2b(b.y); pk.s[6] = f2b(b.z); pk.s[7] = f2b(b.w);
  ((uint4*)out)[i] = pk.v;
}

// ---------- 1024x1024 transpose + convert; z=0,1 -> bf16 (Wq,Wv), z=2 -> f16 (Wf) ----------
__global__ void transpose_cvt(const float* __restrict__ w0, u16* __restrict__ o0,
                              const float* __restrict__ w1, u16* __restrict__ o1,
                              const float* __restrict__ w2, u16* __restrict__ o2) {
  const int z = blockIdx.z;
  const float* in = (z == 0) ? w0 : (z == 1) ? w1 : w2;
  u16* out = (z == 0) ? o0 : (z == 1) ? o1 : o2;
  __shared__ float t[32][33];
  int bx = blockIdx.x * 32, by = blockIdx.y * 32;
  int tx = threadIdx.x, ty = threadIdx.y;   // (32,8)
  #pragma unroll
  for (int i = ty; i < 32; i += 8)
    t[i][tx] = in[(by + i) * DMODEL + bx + tx];
  __syncthreads();
  #pragma unroll
  for (int i = ty; i < 32; i += 8)
    out[(bx + i) * DMODEL + by + tx] = (z == 2) ? f2h(t[tx][i]) : f2b(t[tx][i]);
}

// ---------- per-head V transpose, bf16 -> f16: VbT[((nb*16+h)*64+d)*T + t] ----------
__global__ void transpose_v(const u16* __restrict__ Vb, u16* __restrict__ VbT) {
  __shared__ u16 tl[64 * 66];
  int tb = blockIdx.x, h = blockIdx.y, nb = blockIdx.z;
  int tx = threadIdx.x, ty = threadIdx.y;   // (64,4)
  long long src = (long long)(nb * TSEQ + tb * 64) * DMODEL + h * DKH;
  #pragma unroll
  for (int r = ty; r < 64; r += 4)
    tl[r * 66 + tx] = Vb[src + (long long)r * DMODEL + tx];
  __syncthreads();
  long long dst = (long long)((nb * NHEADS + h) * DKH) * TSEQ + tb * 64;
  #pragma unroll
  for (int r = ty; r < 64; r += 4)
    VbT[dst + (long long)r * TSEQ + tx] = f2h(b2f(tl[tx * 66 + r]));
}

// ---------- GEMM core (R6 config): C = A @ Bt^T + bias, 128x128 tile, BK=64 ----------
template <bool F16, typename CT>
__device__ __forceinline__ void gemm_core(
    u16* As, u16* Bs,   // each [128*64]
    const u16* __restrict__ A, const u16* __restrict__ Bt,
    const float* __restrict__ bias, CT* __restrict__ C,
    const int bm, const int bn, const float osc) {
  const int tid  = threadIdx.x;
  const int wv   = tid >> 6, lane = tid & 63;
  const int wm   = wv >> 1, wn = wv & 1;
  const int l15  = lane & 15, quad = lane >> 4;
  const int srow = lane >> 3, gch = (lane & 7) ^ srow;

  f32x4 acc[4][4];
  #pragma unroll
  for (int i = 0; i < 4; ++i)
    #pragma unroll
    for (int j = 0; j < 4; ++j)
      acc[i][j] = (f32x4){0.f, 0.f, 0.f, 0.f};

  const u16* Ag = A  + (long long)(bm * 128) * DMODEL;
  const u16* Bg = Bt + (long long)(bn * 128) * DMODEL;

  for (int k0 = 0; k0 < DMODEL; k0 += 64) {
    __syncthreads();
    #pragma unroll
    for (int j = 0; j < 4; ++j) {
      int rb = wv * 32 + j * 8;
      gl_lds16(Ag + (long long)(rb + srow) * DMODEL + k0 + gch * 8, As + rb * 64);
      gl_lds16(Bg + (long long)(rb + srow) * DMODEL + k0 + gch * 8, Bs + rb * 64);
    }
    __syncthreads();
    #pragma unroll
    for (int ks = 0; ks < 2; ++ks) {
      #pragma unroll
      for (int mi = 0; mi < 4; ++mi) {
        int ra = wm * 64 + mi * 16 + l15;
        const u16* pa = As + ra * 64 + (((ks * 4 + quad) ^ (ra & 7)) * 8);
        #pragma unroll
        for (int ni = 0; ni < 4; ++ni) {
          int rb = wn * 64 + ni * 16 + l15;
          const u16* pb = Bs + rb * 64 + (((ks * 4 + quad) ^ (rb & 7)) * 8);
          if constexpr (F16)
            acc[mi][ni] = __builtin_amdgcn_mfma_f32_16x16x32_f16(
                *(const half8*)pa, *(const half8*)pb, acc[mi][ni], 0, 0, 0);
          else
            acc[mi][ni] = __builtin_amdgcn_mfma_f32_16x16x32_bf16(
                *(const short8*)pa, *(const short8*)pb, acc[mi][ni], 0, 0, 0);
        }
      }
    }
  }

  #pragma unroll
  for (int ni = 0; ni < 4; ++ni) {
    int col = bn * 128 + wn * 64 + ni * 16 + l15;
    float bvf = bias[col];
    #pragma unroll
    for (int mi = 0; mi < 4; ++mi) {
      int row0 = bm * 128 + wm * 64 + mi * 16 + quad * 4;
      #pragma unroll
      for (int r = 0; r < 4; ++r) {
        float val = (acc[mi][ni][r] + bvf) * osc;
        long long idx = (long long)(row0 + r) * DMODEL + col;
        if constexpr (std::is_same_v<CT, float>) C[idx] = val;
        else                                     C[idx] = f2b(val);
      }
    }
  }
}

// Q and V projections fused on grid z (1024 blocks -> 4 blocks/CU)
__global__ __launch_bounds__(256, 4)
void gemm_qv(const u16* __restrict__ Xq, const u16* __restrict__ Xv,
             const u16* __restrict__ WqT, const u16* __restrict__ WvT,
             const float* __restrict__ bq, const float* __restrict__ bv,
             u16* __restrict__ Qb, u16* __restrict__ Vb) {
  __shared__ u16 As[128 * 64];
  __shared__ u16 Bs[128 * 64];
  const bool isq = (blockIdx.z == 0);
  gemm_core<false, u16>(As, Bs, isq ? Xq : Xv, isq ? WqT : WvT,
                        isq ? bq : bv, isq ? Qb : Vb,
                        blockIdx.x, blockIdx.y, isq ? QSCALE : 1.0f);
}

// out projection: f16 x f16 -> f32
__global__ __launch_bounds__(256, 2)
void gemm_out(const u16* __restrict__ A, const u16* __restrict__ Bt,
              const float* __restrict__ bias, float* __restrict__ C) {
  __shared__ u16 As[128 * 64];
  __shared__ u16 Bs[128 * 64];
  gemm_core<true, float>(As, Bs, A, Bt, bias, C, blockIdx.x, blockIdx.y, 1.0f);
}

// ---------- Flash attention, S^T form, 128-row V tiles (2 barriers / 64 MFMA) ----------
// S^T = V Q'^T (exp2 domain); P = exp2(S^T [+mask]); O^T = V^T P^T; two 64-t halves per tile.
__global__ __launch_bounds__(256, 3)
void attn_kernel(const u16* __restrict__ Qb, const u16* __restrict__ Vb,
                 const u16* __restrict__ VbTh, const int* __restrict__ mask,
                 u16* __restrict__ Ab) {
  __shared__ u16 Vs[128 * 64];       // [t][d] bf16, swizzled (16 KB)
  __shared__ u16 Vts[64 * 128];      // [d][t] f16, swizzled (16 KB)
  __shared__ u16 Ps[4 * 32 * 72];    // per-wave P [q][t-half] f16, stride 72 (18 KB)
  __shared__ float Msf[128];         // additive mask

  const int tid  = threadIdx.x;
  const int qblk = blockIdx.x, h = blockIdx.y, nb = blockIdx.z;
  const int wv   = tid >> 6, lane = tid & 63;
  const int l15  = lane & 15, quad = lane >> 4;
  const int srow = lane >> 3, gch = (lane & 7) ^ srow;

  const int q0 = qblk * 128 + wv * 32;
  const long long rowbase = (long long)nb * TSEQ;
  const long long hd = (long long)((nb * NHEADS + h) * DKH);
  u16* psb = Ps + wv * 32 * 72;

  short8 qf[2][2];   // Q' B-frags (pre-scaled), loaded once
  #pragma unroll
  for (int mi = 0; mi < 2; ++mi)
    #pragma unroll
    for (int ks = 0; ks < 2; ++ks)
      qf[mi][ks] = *(const short8*)(Qb + (rowbase + q0 + mi * 16 + l15) * DMODEL
                                    + h * DKH + ks * 32 + quad * 8);

  f32x4 of[2][4];
  #pragma unroll
  for (int mi = 0; mi < 2; ++mi)
    #pragma unroll
    for (int dt = 0; dt < 4; ++dt)
      of[mi][dt] = (f32x4){0.f, 0.f, 0.f, 0.f};
  float lsum[2] = {0.f, 0.f};
  const half2v one2 = {(__fp16)1.f, (__fp16)1.f};

  for (int vb = 0; vb < TSEQ / 128; ++vb) {
    __syncthreads();
    // ---- stage V tile: Vs 128 rows x 64d; Vts 64 rows x 128t ----
    #pragma unroll
    for (int j = 0; j < 4; ++j) {
      int rb = wv * 32 + j * 8;
      gl_lds16(Vb + (rowbase + vb * 128 + rb + srow) * DMODEL + h * DKH + gch * 8,
               Vs + rb * 64);
    }
    #pragma unroll
    for (int j = 0; j < 4; ++j) {
      int rb = wv * 16 + j * 4;
      int r  = rb + (lane >> 4);
      int g  = (lane & 15) ^ (r & 7);
      gl_lds16(VbTh + (hd + r) * TSEQ + vb * 128 + g * 8, Vts + rb * 128);
    }
    int mv0 = mask[nb * TSEQ + vb * 128 + lane];
    int mv1 = mask[nb * TSEQ + vb * 128 + 64 + lane];
    if (tid < 128) Msf[tid] = mask[nb * TSEQ + vb * 128 + tid] ? 0.f : -INFINITY;
    const bool slowm = __any((mv0 == 0) || (mv1 == 0));   // wave-uniform
    __syncthreads();

    #pragma unroll
    for (int th = 0; th < 2; ++th) {
      // ---- S^T half = V[th] @ Q'^T ----
      f32x4 st[2][4];
      #pragma unroll
      for (int mi = 0; mi < 2; ++mi)
        #pragma unroll
        for (int tt = 0; tt < 4; ++tt)
          st[mi][tt] = (f32x4){0.f, 0.f, 0.f, 0.f};
      #pragma unroll
      for (int tt = 0; tt < 4; ++tt) {
        int r = th * 64 + tt * 16 + l15;
        #pragma unroll
        for (int ks = 0; ks < 2; ++ks) {
          short8 vf = *(const short8*)(Vs + r * 64 + (((ks * 4 + quad) ^ (l15 & 7)) * 8));
          #pragma unroll
          for (int mi = 0; mi < 2; ++mi)
            st[mi][tt] = __builtin_amdgcn_mfma_f32_16x16x32_bf16(vf, qf[mi][ks], st[mi][tt], 0, 0, 0);
        }
      }

      // ---- P = exp2(st [+mask]); fp16 pack; l via dot2 ----
      f32x4 msk[4];
      if (slowm) {
        #pragma unroll
        for (int tt = 0; tt < 4; ++tt)
          msk[tt] = *(const f32x4*)(Msf + th * 64 + tt * 16 + quad * 4);
      }
      #pragma unroll
      for (int mi = 0; mi < 2; ++mi) {
        #pragma unroll
        for (int tt = 0; tt < 4; ++tt) {
          float a0 = st[mi][tt][0], a1 = st[mi][tt][1];
          float a2 = st[mi][tt][2], a3 = st[mi][tt][3];
          if (slowm) { a0 += msk[tt][0]; a1 += msk[tt][1]; a2 += msk[tt][2]; a3 += msk[tt][3]; }
          float p0 = __builtin_amdgcn_exp2f(a0);
          float p1 = __builtin_amdgcn_exp2f(a1);
          float p2 = __builtin_amdgcn_exp2f(a2);
          float p3 = __builtin_amdgcn_exp2f(a3);
          half2v h01 = pkrtz(p0, p1), h23 = pkrtz(p2, p3);
#if __has_builtin(__builtin_amdgcn_fdot2)
          lsum[mi] = __builtin_amdgcn_fdot2(h01, one2, lsum[mi], false);
          lsum[mi] = __builtin_amdgcn_fdot2(h23, one2, lsum[mi], false);
#else
          lsum[mi] += (p0 + p1) + (p2 + p3);
#endif
          uint2 pk; pk.x = h2u(h01); pk.y = h2u(h23);
          *(uint2*)(psb + (mi * 16 + l15) * 72 + tt * 16 + quad * 4) = pk;
        }
      }

      // ---- O^T += V^T[:, th-half] @ P^T (f16 MFMA; Ps wave-private) ----
      #pragma unroll
      for (int kc = 0; kc < 2; ++kc) {
        half8 pf[2];
        #pragma unroll
        for (int mi = 0; mi < 2; ++mi)
          pf[mi] = *(const half8*)(psb + (mi * 16 + l15) * 72 + kc * 32 + quad * 8);
        #pragma unroll
        for (int dt = 0; dt < 4; ++dt) {
          int r = dt * 16 + l15;
          half8 vtf = *(const half8*)(Vts + r * 128 +
                        (((th * 8 + kc * 4 + quad) ^ (l15 & 7)) * 8));
          #pragma unroll
          for (int mi = 0; mi < 2; ++mi)
            of[mi][dt] = __builtin_amdgcn_mfma_f32_16x16x32_f16(vtf, pf[mi], of[mi][dt], 0, 0, 0);
        }
      }
    }
  }

  // ---- epilogue: reduce l across quads, O^T/l -> Ab (f16), 8B stores ----
  #pragma unroll
  for (int mi = 0; mi < 2; ++mi) {
    float l = lsum[mi];
    l += __shfl_xor(l, 16, 64);
    l += __shfl_xor(l, 32, 64);
    float inv = 1.0f / l;
    long long row = rowbase + q0 + mi * 16 + l15;
    #pragma unroll
    for (int dt = 0; dt < 4; ++dt) {
      uint2 o;
      o.x = h2u(pkrtz(of[mi][dt][0] * inv, of[mi][dt][1] * inv));
      o.y = h2u(pkrtz(of[mi][dt][2] * inv, of[mi][dt][3] * inv));
      *(uint2*)(Ab + row * DMODEL + h * DKH + dt * 16 + quad * 4) = o;
    }
  }
}

// ---------- launch ----------
extern "C" void kernel_launch(void* const* d_in, const int* in_sizes, int n_in,
                              void* d_out, int out_size, void* d_ws, size_t ws_size,
                              hipStream_t stream) {
  // order: x_k(0) x_v(1) x_q(2) mask(3) Wk(4) bk(5) Wv(6) bv(7) Wq(8) bq(9) Wf(10) bf(11)
  const float* x_v  = (const float*)d_in[1];
  const float* x_q  = (const float*)d_in[2];
  const int*   mask = (const int*)d_in[3];
  const float* Wv   = (const float*)d_in[6];
  const float* bv   = (const float*)d_in[7];
  const float* Wq   = (const float*)d_in[8];
  const float* bq   = (const float*)d_in[9];
  const float* Wf   = (const float*)d_in[10];
  const float* bfp  = (const float*)d_in[11];

  char* w = (char*)d_ws;
  u16* WqT  = (u16*)(w + 0);            // bf16, 2 MB
  u16* WvT  = (u16*)(w + (2ll << 20));  // bf16
  u16* WfT  = (u16*)(w + (4ll << 20));  // f16
  u16* Xq   = (u16*)(w + (6ll << 20));  // bf16, 16 MB
  u16* Xv   = (u16*)(w + (22ll << 20)); // bf16
  u16* Qb   = (u16*)(w + (38ll << 20)); // bf16 (pre-scaled by QSCALE)
  u16* Vb   = (u16*)(w + (54ll << 20)); // bf16
  u16* VbTh = (u16*)(w + (70ll << 20)); // f16
  u16* Ab   = Xq;                       // f16; alias ok (Xq dead after QV GEMM)

  transpose_cvt<<<dim3(32, 32, 3), dim3(32, 8), 0, stream>>>(Wq, WqT, Wv, WvT, Wf, WfT);

  cvt_bf16<<<dim3(MROWS * DMODEL / 8 / 256, 1, 2), 256, 0, stream>>>(x_q, Xq, x_v, Xv);

  gemm_qv<<<dim3(MROWS / 128, DMODEL / 128, 2), 256, 0, stream>>>(
      Xq, Xv, WqT, WvT, bq, bv, Qb, Vb);

  transpose_v<<<dim3(TSEQ / 64, NHEADS, NBATCH), dim3(64, 4), 0, stream>>>(Vb, VbTh);

  attn_kernel<<<dim3(TSEQ / 128, NHEADS, NBATCH), 256, 0, stream>>>(Qb, Vb, VbTh, mask, Ab);

  gemm_out<<<dim3(MROWS / 128, DMODEL / 128), 256, 0, stream>>>(Ab, WfT, bfp, (float*)d_out);
}

// Round 9
// 331.214 us; speedup vs baseline: 1.1092x; 1.0273x over previous
//
#include <hip/hip_runtime.h>
#include <cstdint>
#include <type_traits>

typedef unsigned short u16;
typedef __attribute__((ext_vector_type(8))) short short8;    // 8 bf16 (4 VGPRs)
typedef __attribute__((ext_vector_type(8))) __fp16 half8;    // 8 fp16 (4 VGPRs)
typedef __attribute__((ext_vector_type(2))) __fp16 half2v;
typedef __attribute__((ext_vector_type(4))) float f32x4;

#define DMODEL 1024
#define TSEQ   2048
#define NHEADS 16
#define DKH    64
#define NBATCH 4
#define MROWS  (NBATCH * TSEQ)   // 8192
#define QSCALE 0.18033688011f    // 0.125 * log2(e), folded into Q projection

// ---------- conversions ----------
__device__ __forceinline__ float b2f(u16 u) {
  union { unsigned int u; float f; } c; c.u = ((unsigned int)u) << 16; return c.f;
}
__device__ __forceinline__ u16 f2b(float f) {   // f32->bf16 RNE
  union { float f; unsigned int u; } c; c.f = f;
  unsigned int u = c.u;
  return (u16)((u + 0x7fffu + ((u >> 16) & 1u)) >> 16);
}
__device__ __forceinline__ half2v pkrtz(float a, float b) {
  return __builtin_amdgcn_cvt_pkrtz(a, b);      // v_cvt_pkrtz_f16_f32
}
__device__ __forceinline__ unsigned h2u(half2v h) {
  unsigned u; __builtin_memcpy(&u, &h, 4); return u;
}
__device__ __forceinline__ u16 f2h(float f) {   // f32->fp16 RTZ
  half2v h = pkrtz(f, 0.f);
  u16 u; __builtin_memcpy(&u, &h, 2); return u;
}

// ---------- async global->LDS, 16B/lane ----------
__device__ __forceinline__ void gl_lds16(const u16* g, u16* l) {
  __builtin_amdgcn_global_load_lds((const __attribute__((address_space(1))) void*)g,
                                   (__attribute__((address_space(3))) void*)l, 16, 0, 0);
}

// ---------- prep: bulk f32->bf16 (x_q,x_v) + 3 weight transposes, one launch ----------
// grid.x = 8192 (cvt) + 3072 (transpose) = 11264 blocks of 256
__global__ void prep(const float* __restrict__ xq, u16* __restrict__ Xq,
                     const float* __restrict__ xv, u16* __restrict__ Xv,
                     const float* __restrict__ Wq, u16* __restrict__ WqT,
                     const float* __restrict__ Wv, u16* __restrict__ WvT,
                     const float* __restrict__ Wf, u16* __restrict__ WfT) {
  const int bid = blockIdx.x, tid = threadIdx.x;
  if (bid < 8192) {
    const float* in = (bid < 4096) ? xq : xv;
    u16* out = (bid < 4096) ? Xq : Xv;
    int i = (bid & 4095) * 256 + tid;
    const float4* p = (const float4*)in + (long long)i * 2;
    float4 a = p[0], b = p[1];
    union { u16 s[8]; uint4 v; } pk;
    pk.s[0] = f2b(a.x); pk.s[1] = f2b(a.y); pk.s[2] = f2b(a.z); pk.s[3] = f2b(a.w);
    pk.s[4] = f2b(b.x); pk.s[5] = f2b(b.y); pk.s[6] = f2b(b.z); pk.s[7] = f2b(b.w);
    ((uint4*)out)[i] = pk.v;
    return;
  }
  const int t = bid - 8192;
  const int z = t >> 10, r = t & 1023;
  const float* in = (z == 0) ? Wq : (z == 1) ? Wv : Wf;
  u16* out = (z == 0) ? WqT : (z == 1) ? WvT : WfT;
  __shared__ float tl[32][33];
  int bx = (r & 31) * 32, by = (r >> 5) * 32;
  int tx = tid & 31, ty = tid >> 5;   // (32,8)
  #pragma unroll
  for (int i = ty; i < 32; i += 8)
    tl[i][tx] = in[(by + i) * DMODEL + bx + tx];
  __syncthreads();
  #pragma unroll
  for (int i = ty; i < 32; i += 8)
    out[(bx + i) * DMODEL + by + tx] = (z == 2) ? f2h(tl[tx][i]) : f2b(tl[tx][i]);
}

// ---------- per-head V transpose, bf16 -> f16: VbT[((nb*16+h)*64+d)*T + t] ----------
__global__ void transpose_v(const u16* __restrict__ Vb, u16* __restrict__ VbT) {
  __shared__ u16 tl[64 * 66];
  int tb = blockIdx.x, h = blockIdx.y, nb = blockIdx.z;
  int tx = threadIdx.x, ty = threadIdx.y;   // (64,4)
  long long src = (long long)(nb * TSEQ + tb * 64) * DMODEL + h * DKH;
  #pragma unroll
  for (int r = ty; r < 64; r += 4)
    tl[r * 66 + tx] = Vb[src + (long long)r * DMODEL + tx];
  __syncthreads();
  long long dst = (long long)((nb * NHEADS + h) * DKH) * TSEQ + tb * 64;
  #pragma unroll
  for (int r = ty; r < 64; r += 4)
    VbT[dst + (long long)r * TSEQ + tx] = f2h(b2f(tl[tx * 66 + r]));
}

// ---------- GEMM core: C = A @ Bt^T + bias, 256x128 tile, BK=64 ----------
// 4 waves (2x2), wave tile 128x64 (8x4 of 16x16 MFMA). Staged bytes/FLOP 25% lower
// than 128x128; 64 MFMA per wave-iter between barriers.
template <bool F16, typename CT>
__device__ __forceinline__ void gemm_core(
    u16* As, u16* Bs,   // As[256*64], Bs[128*64]
    const u16* __restrict__ A, const u16* __restrict__ Bt,
    const float* __restrict__ bias, CT* __restrict__ C,
    const int bm, const int bn, const float osc) {
  const int tid  = threadIdx.x;
  const int wv   = tid >> 6, lane = tid & 63;
  const int wm   = wv >> 1, wn = wv & 1;
  const int l15  = lane & 15, quad = lane >> 4;
  const int srow = lane >> 3, gch = (lane & 7) ^ srow;

  f32x4 acc[8][4];
  #pragma unroll
  for (int i = 0; i < 8; ++i)
    #pragma unroll
    for (int j = 0; j < 4; ++j)
      acc[i][j] = (f32x4){0.f, 0.f, 0.f, 0.f};

  const u16* Ag = A  + (long long)(bm * 256) * DMODEL;
  const u16* Bg = Bt + (long long)(bn * 128) * DMODEL;

  for (int k0 = 0; k0 < DMODEL; k0 += 64) {
    __syncthreads();
    #pragma unroll
    for (int j = 0; j < 8; ++j) {            // A: 256 rows
      int rb = wv * 64 + j * 8;
      gl_lds16(Ag + (long long)(rb + srow) * DMODEL + k0 + gch * 8, As + rb * 64);
    }
    #pragma unroll
    for (int j = 0; j < 4; ++j) {            // B: 128 rows
      int rb = wv * 32 + j * 8;
      gl_lds16(Bg + (long long)(rb + srow) * DMODEL + k0 + gch * 8, Bs + rb * 64);
    }
    __syncthreads();
    #pragma unroll
    for (int ks = 0; ks < 2; ++ks) {
      short8 af[8], bf_[4];
      #pragma unroll
      for (int mi = 0; mi < 8; ++mi) {
        int ra = wm * 128 + mi * 16 + l15;
        af[mi] = *(const short8*)(As + ra * 64 + (((ks * 4 + quad) ^ (ra & 7)) * 8));
      }
      #pragma unroll
      for (int ni = 0; ni < 4; ++ni) {
        int rb = wn * 64 + ni * 16 + l15;
        bf_[ni] = *(const short8*)(Bs + rb * 64 + (((ks * 4 + quad) ^ (rb & 7)) * 8));
      }
      #pragma unroll
      for (int mi = 0; mi < 8; ++mi)
        #pragma unroll
        for (int ni = 0; ni < 4; ++ni) {
          if constexpr (F16)
            acc[mi][ni] = __builtin_amdgcn_mfma_f32_16x16x32_f16(
                *(const half8*)&af[mi], *(const half8*)&bf_[ni], acc[mi][ni], 0, 0, 0);
          else
            acc[mi][ni] = __builtin_amdgcn_mfma_f32_16x16x32_bf16(
                af[mi], bf_[ni], acc[mi][ni], 0, 0, 0);
        }
    }
  }

  #pragma unroll
  for (int ni = 0; ni < 4; ++ni) {
    int col = bn * 128 + wn * 64 + ni * 16 + l15;
    float bvf = bias[col];
    #pragma unroll
    for (int mi = 0; mi < 8; ++mi) {
      int row0 = bm * 256 + wm * 128 + mi * 16 + quad * 4;
      #pragma unroll
      for (int r = 0; r < 4; ++r) {
        float val = (acc[mi][ni][r] + bvf) * osc;
        long long idx = (long long)(row0 + r) * DMODEL + col;
        if constexpr (std::is_same_v<CT, float>) C[idx] = val;
        else                                     C[idx] = f2b(val);
      }
    }
  }
}

// Q and V projections fused on grid z (grid 32x8x2 = 512 blocks, 2/CU)
__global__ __launch_bounds__(256, 2)
void gemm_qv(const u16* __restrict__ Xq, const u16* __restrict__ Xv,
             const u16* __restrict__ WqT, const u16* __restrict__ WvT,
             const float* __restrict__ bq, const float* __restrict__ bv,
             u16* __restrict__ Qb, u16* __restrict__ Vb) {
  __shared__ u16 As[256 * 64];
  __shared__ u16 Bs[128 * 64];
  const bool isq = (blockIdx.z == 0);
  gemm_core<false, u16>(As, Bs, isq ? Xq : Xv, isq ? WqT : WvT,
                        isq ? bq : bv, isq ? Qb : Vb,
                        blockIdx.x, blockIdx.y, isq ? QSCALE : 1.0f);
}

// out projection: f16 x f16 -> f32 (grid 32x8 = 256 blocks)
__global__ __launch_bounds__(256, 2)
void gemm_out(const u16* __restrict__ A, const u16* __restrict__ Bt,
              const float* __restrict__ bias, float* __restrict__ C) {
  __shared__ u16 As[256 * 64];
  __shared__ u16 Bs[128 * 64];
  gemm_core<true, float>(As, Bs, A, Bt, bias, C, blockIdx.x, blockIdx.y, 1.0f);
}

// ---------- Flash attention (R6 config, verbatim): S^T = V Q'^T, P=exp2, O^T = V^T P^T ----------
__global__ __launch_bounds__(256, 4)
void attn_kernel(const u16* __restrict__ Qb, const u16* __restrict__ Vb,
                 const u16* __restrict__ VbTh, const int* __restrict__ mask,
                 u16* __restrict__ Ab) {
  __shared__ u16 Vs[64 * 64];        // [t][d] bf16, swizzled
  __shared__ u16 Vts[64 * 64];       // [d][t] f16, swizzled
  __shared__ u16 Ps[4 * 32 * 72];    // per-wave P [q][t] f16, stride 72
  __shared__ float Msf[64];          // additive mask

  const int tid  = threadIdx.x;
  const int qblk = blockIdx.x, h = blockIdx.y, nb = blockIdx.z;
  const int wv   = tid >> 6, lane = tid & 63;
  const int l15  = lane & 15, quad = lane >> 4;
  const int srow = lane >> 3, gch = (lane & 7) ^ srow;

  const int q0 = qblk * 128 + wv * 32;
  const long long rowbase = (long long)nb * TSEQ;
  const long long hd = (long long)((nb * NHEADS + h) * DKH);
  u16* psb = Ps + wv * 32 * 72;

  short8 qf[2][2];   // Q' B-frags (pre-scaled), loaded once
  #pragma unroll
  for (int mi = 0; mi < 2; ++mi)
    #pragma unroll
    for (int ks = 0; ks < 2; ++ks)
      qf[mi][ks] = *(const short8*)(Qb + (rowbase + q0 + mi * 16 + l15) * DMODEL
                                    + h * DKH + ks * 32 + quad * 8);

  f32x4 of[2][4];
  #pragma unroll
  for (int mi = 0; mi < 2; ++mi)
    #pragma unroll
    for (int dt = 0; dt < 4; ++dt)
      of[mi][dt] = (f32x4){0.f, 0.f, 0.f, 0.f};
  float lsum[2] = {0.f, 0.f};
  const half2v one2 = {(__fp16)1.f, (__fp16)1.f};

  for (int vb = 0; vb < TSEQ / 64; ++vb) {
    __syncthreads();
    #pragma unroll
    for (int j = 0; j < 2; ++j) {
      int rb = wv * 16 + j * 8;
      gl_lds16(Vb   + (rowbase + vb * 64 + rb + srow) * DMODEL + h * DKH + gch * 8, Vs  + rb * 64);
      gl_lds16(VbTh + (hd + rb + srow) * TSEQ + vb * 64 + gch * 8,                  Vts + rb * 64);
    }
    int mv = mask[nb * TSEQ + vb * 64 + lane];
    if (tid < 64) Msf[tid] = mv ? 0.f : -INFINITY;
    const bool slowm = __any(mv == 0);   // wave-uniform
    __syncthreads();

    // ---- S^T = V @ Q'^T ----
    f32x4 st[2][4];
    #pragma unroll
    for (int mi = 0; mi < 2; ++mi)
      #pragma unroll
      for (int tt = 0; tt < 4; ++tt)
        st[mi][tt] = (f32x4){0.f, 0.f, 0.f, 0.f};
    #pragma unroll
    for (int tt = 0; tt < 4; ++tt) {
      int r = tt * 16 + l15;
      #pragma unroll
      for (int ks = 0; ks < 2; ++ks) {
        short8 vf = *(const short8*)(Vs + r * 64 + (((ks * 4 + quad) ^ (l15 & 7)) * 8));
        #pragma unroll
        for (int mi = 0; mi < 2; ++mi)
          st[mi][tt] = __builtin_amdgcn_mfma_f32_16x16x32_bf16(vf, qf[mi][ks], st[mi][tt], 0, 0, 0);
      }
    }

    // ---- P = exp2(st [+mask]); fp16 pack; l via dot2 ----
    f32x4 msk[4];
    if (slowm) {
      #pragma unroll
      for (int tt = 0; tt < 4; ++tt)
        msk[tt] = *(const f32x4*)(Msf + tt * 16 + quad * 4);
    }
    #pragma unroll
    for (int mi = 0; mi < 2; ++mi) {
      #pragma unroll
      for (int tt = 0; tt < 4; ++tt) {
        float a0 = st[mi][tt][0], a1 = st[mi][tt][1];
        float a2 = st[mi][tt][2], a3 = st[mi][tt][3];
        if (slowm) { a0 += msk[tt][0]; a1 += msk[tt][1]; a2 += msk[tt][2]; a3 += msk[tt][3]; }
        float p0 = __builtin_amdgcn_exp2f(a0);
        float p1 = __builtin_amdgcn_exp2f(a1);
        float p2 = __builtin_amdgcn_exp2f(a2);
        float p3 = __builtin_amdgcn_exp2f(a3);
        half2v h01 = pkrtz(p0, p1), h23 = pkrtz(p2, p3);
#if __has_builtin(__builtin_amdgcn_fdot2)
        lsum[mi] = __builtin_amdgcn_fdot2(h01, one2, lsum[mi], false);
        lsum[mi] = __builtin_amdgcn_fdot2(h23, one2, lsum[mi], false);
#else
        lsum[mi] += (p0 + p1) + (p2 + p3);
#endif
        uint2 pk; pk.x = h2u(h01); pk.y = h2u(h23);
        *(uint2*)(psb + (mi * 16 + l15) * 72 + tt * 16 + quad * 4) = pk;
      }
    }

    // ---- O^T += V^T @ P^T (f16 MFMA; Ps wave-private) ----
    #pragma unroll
    for (int kc = 0; kc < 2; ++kc) {
      half8 pf[2];
      #pragma unroll
      for (int mi = 0; mi < 2; ++mi)
        pf[mi] = *(const half8*)(psb + (mi * 16 + l15) * 72 + kc * 32 + quad * 8);
      #pragma unroll
      for (int dt = 0; dt < 4; ++dt) {
        int r = dt * 16 + l15;
        half8 vtf = *(const half8*)(Vts + r * 64 + (((kc * 4 + quad) ^ (l15 & 7)) * 8));
        #pragma unroll
        for (int mi = 0; mi < 2; ++mi)
          of[mi][dt] = __builtin_amdgcn_mfma_f32_16x16x32_f16(vtf, pf[mi], of[mi][dt], 0, 0, 0);
      }
    }
  }

  // ---- epilogue: reduce l across quads, O^T/l -> Ab (f16), 8B stores ----
  #pragma unroll
  for (int mi = 0; mi < 2; ++mi) {
    float l = lsum[mi];
    l += __shfl_xor(l, 16, 64);
    l += __shfl_xor(l, 32, 64);
    float inv = 1.0f / l;
    long long row = rowbase + q0 + mi * 16 + l15;
    #pragma unroll
    for (int dt = 0; dt < 4; ++dt) {
      uint2 o;
      o.x = h2u(pkrtz(of[mi][dt][0] * inv, of[mi][dt][1] * inv));
      o.y = h2u(pkrtz(of[mi][dt][2] * inv, of[mi][dt][3] * inv));
      *(uint2*)(Ab + row * DMODEL + h * DKH + dt * 16 + quad * 4) = o;
    }
  }
}

// ---------- launch ----------
extern "C" void kernel_launch(void* const* d_in, const int* in_sizes, int n_in,
                              void* d_out, int out_size, void* d_ws, size_t ws_size,
                              hipStream_t stream) {
  // order: x_k(0) x_v(1) x_q(2) mask(3) Wk(4) bk(5) Wv(6) bv(7) Wq(8) bq(9) Wf(10) bf(11)
  const float* x_v  = (const float*)d_in[1];
  const float* x_q  = (const float*)d_in[2];
  const int*   mask = (const int*)d_in[3];
  const float* Wv   = (const float*)d_in[6];
  const float* bv   = (const float*)d_in[7];
  const float* Wq   = (const float*)d_in[8];
  const float* bq   = (const float*)d_in[9];
  const float* Wf   = (const float*)d_in[10];
  const float* bfp  = (const float*)d_in[11];

  char* w = (char*)d_ws;
  u16* WqT  = (u16*)(w + 0);            // bf16, 2 MB
  u16* WvT  = (u16*)(w + (2ll << 20));  // bf16
  u16* WfT  = (u16*)(w + (4ll << 20));  // f16
  u16* Xq   = (u16*)(w + (6ll << 20));  // bf16, 16 MB
  u16* Xv   = (u16*)(w + (22ll << 20)); // bf16
  u16* Qb   = (u16*)(w + (38ll << 20)); // bf16 (pre-scaled by QSCALE)
  u16* Vb   = (u16*)(w + (54ll << 20)); // bf16
  u16* VbTh = (u16*)(w + (70ll << 20)); // f16
  u16* Ab   = Xq;                       // f16; alias ok (Xq dead after QV GEMM)

  prep<<<11264, 256, 0, stream>>>(x_q, Xq, x_v, Xv, Wq, WqT, Wv, WvT, Wf, WfT);

  gemm_qv<<<dim3(MROWS / 256, DMODEL / 128, 2), 256, 0, stream>>>(
      Xq, Xv, WqT, WvT, bq, bv, Qb, Vb);

  transpose_v<<<dim3(TSEQ / 64, NHEADS, NBATCH), dim3(64, 4), 0, stream>>>(Vb, VbTh);

  attn_kernel<<<dim3(TSEQ / 128, NHEADS, NBATCH), 256, 0, stream>>>(Qb, Vb, VbTh, mask, Ab);

  gemm_out<<<dim3(MROWS / 256, DMODEL / 128), 256, 0, stream>>>(Ab, WfT, bfp, (float*)d_out);
}